// Round 1
// baseline (962.399 us; speedup 1.0000x reference)
//
#include <hip/hip_runtime.h>

#define NN 50000
#define NE 600000

typedef __attribute__((ext_vector_type(8))) short short8;
typedef __attribute__((ext_vector_type(4))) float f32x4;

__device__ __forceinline__ float bf2f(unsigned short u){
  union { unsigned int i; float f; } c; c.i = ((unsigned int)u) << 16; return c.f;
}
__device__ __forceinline__ unsigned short f2b(float f){
  union { float f; unsigned int i; } c; c.f = f;
  unsigned int i = c.i;
  return (unsigned short)((i + 0x7FFFu + ((i >> 16) & 1u)) >> 16);
}

// ---------- fp32 -> bf16 convert (vectorized x4) ----------
__global__ void k_cvt_bf16(const float* __restrict__ in, unsigned short* __restrict__ out, int n4){
  int i = blockIdx.x*blockDim.x + threadIdx.x;
  if (i >= n4) return;
  float4 v = ((const float4*)in)[i];
  uint2 o;
  o.x = (unsigned)f2b(v.x) | ((unsigned)f2b(v.y) << 16);
  o.y = (unsigned)f2b(v.z) | ((unsigned)f2b(v.w) << 16);
  ((uint2*)out)[i] = o;
}

// ---------- CSR build ----------
__global__ void k_hist(const int* __restrict__ dst, int* __restrict__ deg, int e){
  int i = blockIdx.x*blockDim.x + threadIdx.x;
  if (i < e) atomicAdd(&deg[dst[i]], 1);
}

__global__ void k_scan(const int* __restrict__ deg, int* __restrict__ row_off, int* __restrict__ cur, int n){
  __shared__ int wsum[16];
  __shared__ int carry_s;
  int tid = threadIdx.x;
  int lane = tid & 63, wid = tid >> 6;
  if (tid == 0) carry_s = 0;
  __syncthreads();
  for (int base = 0; base < n; base += 1024){
    int i = base + tid;
    int v = (i < n) ? deg[i] : 0;
    int x = v;
    #pragma unroll
    for (int off2=1; off2<64; off2<<=1){
      int t = __shfl_up(x, off2);
      if (lane >= off2) x += t;
    }
    if (lane == 63) wsum[wid] = x;
    __syncthreads();
    if (wid == 0){
      int wv = (lane < 16) ? wsum[lane] : 0;
      #pragma unroll
      for (int off2=1; off2<16; off2<<=1){
        int t = __shfl_up(wv, off2);
        if (lane >= off2) wv += t;
      }
      if (lane < 16) wsum[lane] = wv;
    }
    __syncthreads();
    int wpre = (wid > 0) ? wsum[wid-1] : 0;
    int carry = carry_s;
    int excl = carry + wpre + x - v;
    if (i < n){ row_off[i] = excl; cur[i] = excl; }
    __syncthreads();
    if (tid == 1023) carry_s = carry + wsum[15];
    __syncthreads();
  }
  if (tid == 0) row_off[n] = carry_s;
}

__global__ void k_fill(const int* __restrict__ src, const int* __restrict__ dst,
                       int* __restrict__ cur, int* __restrict__ col, int e){
  int i = blockIdx.x*blockDim.x + threadIdx.x;
  if (i >= e) return;
  int d = dst[i];
  int pos = atomicAdd(&cur[d], 1);
  col[pos] = src[i];
}

// ---------- weight transpose+convert: W[K][N] f32 -> WT[N][K] bf16 ----------
__global__ void k_wconv(const float* __restrict__ W, unsigned short* __restrict__ out,
                        int total, int log2K, int N){
  int i = blockIdx.x*blockDim.x + threadIdx.x;
  if (i >= total) return;
  int K = 1 << log2K;
  int k = i & (K-1);
  int n = i >> log2K;
  out[i] = f2b(W[k*N + n]);
}

// ---------- aggregation: x = h + mean_{in-edges}(h[src]) ; D=128, bf16 ----------
__global__ void k_agg(const unsigned short* __restrict__ h, const int* __restrict__ row_off,
                      const int* __restrict__ col, unsigned short* __restrict__ x){
  int lane = threadIdx.x & 63;
  int node = blockIdx.x*4 + (threadIdx.x >> 6);
  if (node >= NN) return;
  int beg = row_off[node], end = row_off[node+1];
  const unsigned int* hp = (const unsigned int*)h;
  float a0 = 0.f, a1 = 0.f;
  for (int e = beg; e < end; ++e){
    int s = col[e];
    unsigned int v = hp[s*64 + lane];
    a0 += bf2f((unsigned short)(v & 0xFFFFu));
    a1 += bf2f((unsigned short)(v >> 16));
  }
  float inv = (end > beg) ? (1.0f / (float)(end - beg)) : 1.0f;
  unsigned int hv = hp[node*64 + lane];
  float x0 = bf2f((unsigned short)(hv & 0xFFFFu)) + a0 * inv;
  float x1 = bf2f((unsigned short)(hv >> 16)) + a1 * inv;
  ((unsigned int*)x)[node*64 + lane] = (unsigned)f2b(x0) | ((unsigned)f2b(x1) << 16);
}

// ---------- bf16 MFMA GEMM: Y[M][N] = A[M][K] @ BT[N][K]^T + bias ----------
template<int KSTEPS, int NTILES>
__global__ __launch_bounds__(256) void k_gemm(const unsigned short* __restrict__ A,
                                              const unsigned short* __restrict__ BT,
                                              const float* __restrict__ bias,
                                              float* __restrict__ Y, int M){
  constexpr int K = KSTEPS*32;
  constexpr int N = NTILES*16;
  int lane = threadIdx.x & 63;
  int wave = threadIdx.x >> 6;
  int row0 = (blockIdx.x*4 + wave)*16;
  if (row0 >= M) return;
  int r = lane & 15;   // A row offset / B col offset / C col offset
  int g = lane >> 4;   // k-group
  int arow = row0 + r; if (arow > M-1) arow = M-1;
  f32x4 acc[NTILES];
  #pragma unroll
  for (int t=0;t<NTILES;++t) acc[t] = (f32x4){0.f,0.f,0.f,0.f};
  #pragma unroll
  for (int kk=0; kk<KSTEPS; ++kk){
    short8 af = *(const short8*)(A + (size_t)arow*K + kk*32 + g*8);
    #pragma unroll
    for (int t=0;t<NTILES;++t){
      short8 bf = *(const short8*)(BT + (size_t)(t*16 + r)*K + kk*32 + g*8);
      acc[t] = __builtin_amdgcn_mfma_f32_16x16x32_bf16(af, bf, acc[t], 0, 0, 0);
    }
  }
  #pragma unroll
  for (int t=0;t<NTILES;++t){
    int c = t*16 + r;
    float bv = bias[c];
    #pragma unroll
    for (int j=0;j<4;++j){
      int row = row0 + g*4 + j;
      if (row < M) Y[(size_t)row*N + c] = acc[t][j] + bv;
    }
  }
}

// ---------- BN column stats: per-block partial sum/sumsq ----------
__global__ void k_stats(const float* __restrict__ Y, float* __restrict__ part,
                        int M, int N, int log2N){
  int tid = threadIdx.x;
  int colC = tid & (N-1);
  int rlane = tid >> log2N;
  int rpi = 256 >> log2N;
  float s = 0.f, ss = 0.f;
  for (int row = blockIdx.x*rpi + rlane; row < M; row += gridDim.x*rpi){
    float v = Y[(size_t)row*N + colC];
    s += v; ss += v*v;
  }
  __shared__ float shs[256], shq[256];
  shs[tid] = s; shq[tid] = ss;
  __syncthreads();
  if (rlane == 0){
    for (int k2=1; k2<rpi; ++k2){ s += shs[k2*N + colC]; ss += shq[k2*N + colC]; }
    part[((size_t)blockIdx.x*N + colC)*2 + 0] = s;
    part[((size_t)blockIdx.x*N + colC)*2 + 1] = ss;
  }
}

__global__ void k_finalize(const float* __restrict__ part, const float* __restrict__ g,
                           const float* __restrict__ be, float* __restrict__ ab,
                           int M, int N, int nblk){
  int c = threadIdx.x;
  if (c >= N) return;
  float s=0.f, ss=0.f;
  for (int b=0;b<nblk;++b){ s += part[((size_t)b*N+c)*2]; ss += part[((size_t)b*N+c)*2+1]; }
  float mu = s / (float)M;
  float var = ss/(float)M - mu*mu;
  var = fmaxf(var, 0.f);
  float rstd = rsqrtf(var + 1e-5f);
  float a = g[c]*rstd;
  ((float2*)ab)[c] = make_float2(a, be[c] - mu*a);
}

// ---------- BN apply + relu ----------
__global__ void k_apply_bf16(const float* __restrict__ Y, const float* __restrict__ ab,
                             unsigned short* __restrict__ out, int total, int mask){
  int i4 = blockIdx.x*blockDim.x + threadIdx.x;
  int i = i4*4;
  if (i >= total) return;
  float4 v = ((const float4*)Y)[i4];
  const float2* abp = (const float2*)ab;
  int c = i & mask;
  float2 p0 = abp[c], p1 = abp[c+1], p2 = abp[c+2], p3 = abp[c+3];
  float o0 = fmaxf(fmaf(v.x, p0.x, p0.y), 0.f);
  float o1 = fmaxf(fmaf(v.y, p1.x, p1.y), 0.f);
  float o2 = fmaxf(fmaf(v.z, p2.x, p2.y), 0.f);
  float o3 = fmaxf(fmaf(v.w, p3.x, p3.y), 0.f);
  uint2 o;
  o.x = (unsigned)f2b(o0) | ((unsigned)f2b(o1)<<16);
  o.y = (unsigned)f2b(o2) | ((unsigned)f2b(o3)<<16);
  ((uint2*)out)[i4] = o;
}

__global__ void k_apply_f32(const float* __restrict__ Y, const float* __restrict__ ab,
                            float* __restrict__ out, int total, int mask){
  int i4 = blockIdx.x*blockDim.x + threadIdx.x;
  int i = i4*4;
  if (i >= total) return;
  float4 v = ((const float4*)Y)[i4];
  const float2* abp = (const float2*)ab;
  int c = i & mask;
  float2 p0 = abp[c], p1 = abp[c+1], p2 = abp[c+2], p3 = abp[c+3];
  float4 o;
  o.x = fmaxf(fmaf(v.x, p0.x, p0.y), 0.f);
  o.y = fmaxf(fmaf(v.y, p1.x, p1.y), 0.f);
  o.z = fmaxf(fmaf(v.z, p2.x, p2.y), 0.f);
  o.w = fmaxf(fmaf(v.w, p3.x, p3.y), 0.f);
  ((float4*)out)[i4] = o;
}

extern "C" void kernel_launch(void* const* d_in, const int* in_sizes, int n_in,
                              void* d_out, int out_size, void* d_ws, size_t ws_size,
                              hipStream_t stream) {
  const float* features = (const float*)d_in[0];
  const int* src = (const int*)d_in[1];
  const int* dst = (const int*)d_in[2];
  const float *Wp[6], *bp[6], *gp[6], *bep[6];
  int p = 3;
  for (int l=0;l<3;++l){
    Wp[2*l]   = (const float*)d_in[p++]; bp[2*l]   = (const float*)d_in[p++];
    gp[2*l]   = (const float*)d_in[p++]; bep[2*l]  = (const float*)d_in[p++];
    Wp[2*l+1] = (const float*)d_in[p++]; bp[2*l+1] = (const float*)d_in[p++];
    gp[2*l+1] = (const float*)d_in[p++]; bep[2*l+1]= (const float*)d_in[p++];
  }

  size_t off = 0;
  char* base = (char*)d_ws;
  auto carve = [&](size_t bytes)->char* {
    char* q = base + off; off += (bytes + 255) & ~(size_t)255; return q;
  };
  int* deg     = (int*)carve((size_t)NN*4);
  int* row_off = (int*)carve((size_t)(NN+1)*4);
  int* cur     = (int*)carve((size_t)NN*4);
  int* col     = (int*)carve((size_t)NE*4);
  unsigned short* wt[6];
  for (int i=0;i<6;++i) wt[i] = (unsigned short*)carve(128*128*2);
  unsigned short* B0 = (unsigned short*)carve((size_t)NN*128*2);
  unsigned short* B1 = (unsigned short*)carve((size_t)NN*128*2);
  float* Yb   = (float*)carve((size_t)NN*128*4);
  float* part = (float*)carve((size_t)128*128*2*4);
  float* ab   = (float*)carve((size_t)128*2*4);

  hipMemsetAsync(deg, 0, (size_t)NN*4, stream);
  k_cvt_bf16<<<(NN*128/4 + 255)/256, 256, 0, stream>>>(features, B0, NN*128/4);
  k_hist<<<(NE+255)/256, 256, 0, stream>>>(dst, deg, NE);
  k_scan<<<1, 1024, 0, stream>>>(deg, row_off, cur, NN);
  k_fill<<<(NE+255)/256, 256, 0, stream>>>(src, dst, cur, col, NE);

  const int wK[6] = {128,128,128,128,128,64};
  const int wN[6] = {128,128,128,128,64,64};
  for (int i=0;i<6;++i){
    int total = wK[i]*wN[i];
    int l2k = (wK[i]==128)?7:6;
    k_wconv<<<(total+255)/256, 256, 0, stream>>>(Wp[i], wt[i], total, l2k, wN[i]);
  }

  unsigned short* hcur = B0;
  unsigned short* hoth = B1;
  const int gemm_grid = (NN + 63)/64;
  for (int l=0;l<3;++l){
    int N1 = (l==2)?64:128;
    int N2 = (l==2)?64:128;
    // aggregate: hcur (D=128) -> hoth
    k_agg<<<NN/4, 256, 0, stream>>>(hcur, row_off, col, hoth);
    // gemm1: K=128, N=N1
    if (N1==128) k_gemm<4,8><<<gemm_grid,256,0,stream>>>(hoth, wt[2*l], bp[2*l], Yb, NN);
    else         k_gemm<4,4><<<gemm_grid,256,0,stream>>>(hoth, wt[2*l], bp[2*l], Yb, NN);
    k_stats<<<128,256,0,stream>>>(Yb, part, NN, N1, (N1==128)?7:6);
    k_finalize<<<1,128,0,stream>>>(part, gp[2*l], bep[2*l], ab, NN, N1, 128);
    k_apply_bf16<<<((NN*N1/4)+255)/256,256,0,stream>>>(Yb, ab, hcur, NN*N1, N1-1);
    // gemm2: K=N1, N=N2
    if (l==2) k_gemm<2,4><<<gemm_grid,256,0,stream>>>(hcur, wt[2*l+1], bp[2*l+1], Yb, NN);
    else      k_gemm<4,8><<<gemm_grid,256,0,stream>>>(hcur, wt[2*l+1], bp[2*l+1], Yb, NN);
    k_stats<<<128,256,0,stream>>>(Yb, part, NN, N2, (N2==128)?7:6);
    k_finalize<<<1,128,0,stream>>>(part, gp[2*l+1], bep[2*l+1], ab, NN, N2, 128);
    if (l==2){
      k_apply_f32<<<((NN*64/4)+255)/256,256,0,stream>>>(Yb, ab, (float*)d_out, NN*64, 63);
    } else {
      k_apply_bf16<<<((NN*128/4)+255)/256,256,0,stream>>>(Yb, ab, hoth, NN*128, 127);
      unsigned short* t = hcur; hcur = hoth; hoth = t;
    }
  }
}

// Round 2
// 394.362 us; speedup vs baseline: 2.4404x; 2.4404x over previous
//
#include <hip/hip_runtime.h>

#define NN 50000
#define NE 600000

typedef __attribute__((ext_vector_type(8))) short short8;
typedef __attribute__((ext_vector_type(4))) float f32x4;

__device__ __forceinline__ float bf2f(unsigned short u){
  union { unsigned int i; float f; } c; c.i = ((unsigned int)u) << 16; return c.f;
}
__device__ __forceinline__ float lof(unsigned v){
  union { unsigned int i; float f; } c; c.i = v << 16; return c.f;
}
__device__ __forceinline__ float hif(unsigned v){
  union { unsigned int i; float f; } c; c.i = v & 0xFFFF0000u; return c.f;
}
__device__ __forceinline__ unsigned short f2b(float f){
  union { float f; unsigned int i; } c; c.f = f;
  unsigned int i = c.i;
  return (unsigned short)((i + 0x7FFFu + ((i >> 16) & 1u)) >> 16);
}

// ---------- fp32 -> bf16 convert ----------
__global__ void k_cvt_bf16(const float* __restrict__ in, unsigned short* __restrict__ out, int n4){
  int i = blockIdx.x*blockDim.x + threadIdx.x;
  if (i >= n4) return;
  float4 v = ((const float4*)in)[i];
  uint2 o;
  o.x = (unsigned)f2b(v.x) | ((unsigned)f2b(v.y) << 16);
  o.y = (unsigned)f2b(v.z) | ((unsigned)f2b(v.w) << 16);
  ((uint2*)out)[i] = o;
}

// ---------- CSR build ----------
__global__ void k_hist(const int* __restrict__ dst, int* __restrict__ deg, int e){
  int i = blockIdx.x*blockDim.x + threadIdx.x;
  if (i < e) atomicAdd(&deg[dst[i]], 1);
}

__global__ void k_offsets(const int* __restrict__ deg, int* __restrict__ row_off,
                          int* __restrict__ cur, int* __restrict__ total){
  __shared__ int ws[4];
  __shared__ int wbase[4];
  int tid = threadIdx.x, lane = tid & 63, wid = tid >> 6;
  int i = blockIdx.x*256 + tid;
  int v = (i < NN) ? deg[i] : 0;
  int x = v;
  #pragma unroll
  for (int o=1; o<64; o<<=1){
    int t = __shfl_up(x, o);
    if (lane >= o) x += t;
  }
  if (lane == 63) ws[wid] = x;
  __syncthreads();
  if (tid == 0){
    int s0=ws[0], s1=ws[1], s2=ws[2], s3=ws[3];
    int b = atomicAdd(total, s0+s1+s2+s3);
    wbase[0]=b; wbase[1]=b+s0; wbase[2]=b+s0+s1; wbase[3]=b+s0+s1+s2;
  }
  __syncthreads();
  if (i < NN){
    int excl = wbase[wid] + x - v;
    row_off[i] = excl;
    cur[i] = excl;
  }
}

__global__ void k_fill(const int* __restrict__ src, const int* __restrict__ dst,
                       int* __restrict__ cur, int* __restrict__ col, int e){
  int i = blockIdx.x*blockDim.x + threadIdx.x;
  if (i >= e) return;
  int d = dst[i];
  int pos = atomicAdd(&cur[d], 1);
  col[pos] = src[i];
}

// ---------- fused weight transpose+convert: 6 jobs, W[K][N] f32 -> WT[N][K] bf16 ----------
struct W6 { const float* w[6]; unsigned short* o[6]; };
__global__ void k_wconv(W6 jb){
  int i = blockIdx.x*256 + threadIdx.x;
  if (i >= 77824) return;
  int job, base, K, N;
  if (i < 65536){ job = i >> 14; base = job << 14; K = 128; N = 128; }
  else if (i < 73728){ job = 4; base = 65536; K = 128; N = 64; }
  else { job = 5; base = 73728; K = 64; N = 64; }
  int t = i - base;
  int k = t & (K-1);
  int n = t / K;
  jb.o[job][t] = f2b(jb.w[job][k*N + n]);
}

// ---------- aggregation: x = h + mean(h[neigh]); optional fused relu(bn) via ab ----------
template<bool APPLY>
__global__ __launch_bounds__(256) void k_agg(const unsigned short* __restrict__ H,
    const float* __restrict__ ab, const int* __restrict__ row_off,
    const int* __restrict__ deg, const int* __restrict__ col,
    unsigned short* __restrict__ X){
  int lane = threadIdx.x & 63;
  int node = blockIdx.x*4 + (threadIdx.x >> 6);
  if (node >= NN) return;
  const unsigned* hp = (const unsigned*)H;
  unsigned sv = hp[(size_t)node*64 + lane];
  int beg = row_off[node];
  int d = deg[node];
  float a0=0.f, b0=0.f, a1=0.f, b1=0.f;
  if (APPLY){
    float2 p0 = ((const float2*)ab)[2*lane];
    float2 p1 = ((const float2*)ab)[2*lane+1];
    a0=p0.x; b0=p0.y; a1=p1.x; b1=p1.y;
  }
  float s0=0.f, s1=0.f;
  for (int base=0; base<d; base+=64){
    int cnt = d - base; if (cnt > 64) cnt = 64;
    int cv = 0;
    if (lane < cnt) cv = col[beg + base + lane];
    int j = 0;
    for (; j+4 <= cnt; j += 4){
      int i0=__shfl(cv,j), i1=__shfl(cv,j+1), i2=__shfl(cv,j+2), i3=__shfl(cv,j+3);
      unsigned v0 = hp[(size_t)i0*64 + lane];
      unsigned v1 = hp[(size_t)i1*64 + lane];
      unsigned v2 = hp[(size_t)i2*64 + lane];
      unsigned v3 = hp[(size_t)i3*64 + lane];
      float x;
      x = lof(v0); if (APPLY) x = fmaxf(fmaf(x,a0,b0),0.f); s0 += x;
      x = hif(v0); if (APPLY) x = fmaxf(fmaf(x,a1,b1),0.f); s1 += x;
      x = lof(v1); if (APPLY) x = fmaxf(fmaf(x,a0,b0),0.f); s0 += x;
      x = hif(v1); if (APPLY) x = fmaxf(fmaf(x,a1,b1),0.f); s1 += x;
      x = lof(v2); if (APPLY) x = fmaxf(fmaf(x,a0,b0),0.f); s0 += x;
      x = hif(v2); if (APPLY) x = fmaxf(fmaf(x,a1,b1),0.f); s1 += x;
      x = lof(v3); if (APPLY) x = fmaxf(fmaf(x,a0,b0),0.f); s0 += x;
      x = hif(v3); if (APPLY) x = fmaxf(fmaf(x,a1,b1),0.f); s1 += x;
    }
    for (; j < cnt; ++j){
      int i0 = __shfl(cv, j);
      unsigned v0 = hp[(size_t)i0*64 + lane];
      float x = lof(v0); if (APPLY) x = fmaxf(fmaf(x,a0,b0),0.f); s0 += x;
      x = hif(v0); if (APPLY) x = fmaxf(fmaf(x,a1,b1),0.f); s1 += x;
    }
  }
  float h0 = lof(sv), h1 = hif(sv);
  if (APPLY){ h0 = fmaxf(fmaf(h0,a0,b0),0.f); h1 = fmaxf(fmaf(h1,a1,b1),0.f); }
  float inv = 1.f / (float)(d > 0 ? d : 1);
  float x0 = h0 + s0*inv;
  float x1 = h1 + s1*inv;
  ((unsigned*)X)[(size_t)node*64 + lane] = (unsigned)f2b(x0) | ((unsigned)f2b(x1) << 16);
}

// ---------- GEMM (bf16 MFMA) + fused BN stats epilogue; optional fused apply on A-load ----------
// Y[M][N] = act(A)[M][K] @ BT[N][K]^T   (bias dropped: it cancels inside BatchNorm)
template<int KSTEPS, int NTILES, bool APPLY>
__global__ __launch_bounds__(256) void k_gemm(const unsigned short* __restrict__ A,
    const unsigned short* __restrict__ BT, const float* __restrict__ abIn,
    unsigned short* __restrict__ Y, float* __restrict__ statsAcc, int M){
  constexpr int K = KSTEPS*32;
  constexpr int N = NTILES*16;
  __shared__ float red[2*N];
  int tid = threadIdx.x;
  int lane = tid & 63, wave = tid >> 6;
  int row0 = (blockIdx.x*4 + wave)*16;
  bool valid = (row0 < M);
  int r = lane & 15, g = lane >> 4;
  f32x4 acc[NTILES];
  #pragma unroll
  for (int t=0;t<NTILES;++t) acc[t] = (f32x4){0.f,0.f,0.f,0.f};
  if (valid){
    int arow = row0 + r;
    #pragma unroll
    for (int kk=0; kk<KSTEPS; ++kk){
      short8 af = *(const short8*)(A + (size_t)arow*K + kk*32 + g*8);
      if (APPLY){
        #pragma unroll
        for (int j=0;j<8;++j){
          float2 p = ((const float2*)abIn)[kk*32 + g*8 + j];
          float v = fmaxf(fmaf(bf2f((unsigned short)af[j]), p.x, p.y), 0.f);
          af[j] = (short)f2b(v);
        }
      }
      #pragma unroll
      for (int t=0;t<NTILES;++t){
        short8 bf = *(const short8*)(BT + (size_t)(t*16 + r)*K + kk*32 + g*8);
        acc[t] = __builtin_amdgcn_mfma_f32_16x16x32_bf16(af, bf, acc[t], 0, 0, 0);
      }
    }
  }
  for (int i=tid; i<2*N; i+=256) red[i] = 0.f;
  __syncthreads();
  if (valid){
    #pragma unroll
    for (int t=0;t<NTILES;++t){
      int c = t*16 + r;
      float ys = 0.f, yq = 0.f;
      #pragma unroll
      for (int j=0;j<4;++j){
        float y = acc[t][j];
        Y[(size_t)(row0 + g*4 + j)*N + c] = (unsigned short)f2b(y);
        ys += y; yq += y*y;
      }
      ys += __shfl_xor(ys, 16); ys += __shfl_xor(ys, 32);
      yq += __shfl_xor(yq, 16); yq += __shfl_xor(yq, 32);
      if (g == 0){
        atomicAdd(&red[c], ys);
        atomicAdd(&red[N+c], yq);
      }
    }
  }
  __syncthreads();
  for (int i=tid; i<2*N; i+=256) atomicAdd(&statsAcc[i], red[i]);
}

// ---------- finalize BN coefficients: a = g*rstd, b = be - mu*a ----------
__global__ void k_fin(const float* __restrict__ st, const float* __restrict__ gam,
                      const float* __restrict__ bet, float* __restrict__ ab, int N){
  int c = threadIdx.x;
  if (c >= N) return;
  float mu = st[c] * (1.f/(float)NN);
  float var = fmaxf(st[N+c] * (1.f/(float)NN) - mu*mu, 0.f);
  float a = gam[c] * rsqrtf(var + 1e-5f);
  ((float2*)ab)[c] = make_float2(a, bet[c] - mu*a);
}

// ---------- final output: out = relu(a*y+b), f32 ----------
__global__ void k_final(const unsigned short* __restrict__ Y, const float* __restrict__ ab,
                        float* __restrict__ out){
  int i = blockIdx.x*256 + threadIdx.x;   // over NN*32 uints (2 bf16 each)
  if (i >= NN*32) return;
  unsigned v = ((const unsigned*)Y)[i];
  int c = (i & 31)*2;
  float2 p0 = ((const float2*)ab)[c], p1 = ((const float2*)ab)[c+1];
  float o0 = fmaxf(fmaf(lof(v), p0.x, p0.y), 0.f);
  float o1 = fmaxf(fmaf(hif(v), p1.x, p1.y), 0.f);
  ((float2*)out)[i] = make_float2(o0, o1);
}

extern "C" void kernel_launch(void* const* d_in, const int* in_sizes, int n_in,
                              void* d_out, int out_size, void* d_ws, size_t ws_size,
                              hipStream_t stream) {
  const float* features = (const float*)d_in[0];
  const int* src = (const int*)d_in[1];
  const int* dst = (const int*)d_in[2];
  const float *Wp[6], *gp[6], *bep[6];
  int p = 3;
  for (int l=0;l<3;++l){
    Wp[2*l]   = (const float*)d_in[p]; p++; p++; /* skip b1 */
    gp[2*l]   = (const float*)d_in[p-1+0]; // careful: order W1,b1,g1,be1
    // re-do explicitly below
    p -= 2;
    Wp[2*l]   = (const float*)d_in[p++];
    p++; // b1 unused
    gp[2*l]   = (const float*)d_in[p++];
    bep[2*l]  = (const float*)d_in[p++];
    Wp[2*l+1] = (const float*)d_in[p++];
    p++; // b2 unused
    gp[2*l+1] = (const float*)d_in[p++];
    bep[2*l+1]= (const float*)d_in[p++];
  }

  size_t off = 0;
  char* base = (char*)d_ws;
  auto carve = [&](size_t bytes)->char* {
    char* q = base + off; off += (bytes + 255) & ~(size_t)255; return q;
  };
  // zero-init region: deg + total + 6 stats buffers (contiguous)
  int* deg     = (int*)carve((size_t)NN*4);
  int* total   = (int*)carve(4);
  float* stats[6];
  for (int i=0;i<6;++i) stats[i] = (float*)carve(256*4);
  size_t zbytes = (size_t)(base + off - (char*)deg);

  int* row_off = (int*)carve((size_t)NN*4);
  int* cur     = (int*)carve((size_t)NN*4);
  int* col     = (int*)carve((size_t)NE*4);
  unsigned short* wt[6];
  for (int i=0;i<6;++i) wt[i] = (unsigned short*)carve(128*128*2);
  float* ab[6];
  for (int i=0;i<6;++i) ab[i] = (float*)carve(128*2*4);
  unsigned short* H0 = (unsigned short*)carve((size_t)NN*128*2);
  unsigned short* X  = (unsigned short*)carve((size_t)NN*128*2);
  unsigned short* Y1 = (unsigned short*)carve((size_t)NN*128*2);
  unsigned short* Y2 = (unsigned short*)carve((size_t)NN*128*2);

  hipMemsetAsync(deg, 0, zbytes, stream);
  k_cvt_bf16<<<(NN*32 + 255)/256, 256, 0, stream>>>(features, H0, NN*32);
  k_hist<<<(NE+255)/256, 256, 0, stream>>>(dst, deg, NE);
  k_offsets<<<(NN+255)/256, 256, 0, stream>>>(deg, row_off, cur, total);
  k_fill<<<(NE+255)/256, 256, 0, stream>>>(src, dst, cur, col, NE);

  W6 jb;
  for (int i=0;i<6;++i){ jb.w[i] = Wp[i]; jb.o[i] = wt[i]; }
  k_wconv<<<(77824+255)/256, 256, 0, stream>>>(jb);

  const int agg_grid  = (NN + 3)/4;
  const int gemm_grid = (NN + 63)/64;

  // ---- layer 0 ----
  k_agg<false><<<agg_grid, 256, 0, stream>>>(H0, nullptr, row_off, deg, col, X);
  k_gemm<4,8,false><<<gemm_grid, 256, 0, stream>>>(X, wt[0], nullptr, Y1, stats[0], NN);
  k_fin<<<1, 128, 0, stream>>>(stats[0], gp[0], bep[0], ab[0], 128);
  k_gemm<4,8,true><<<gemm_grid, 256, 0, stream>>>(Y1, wt[1], ab[0], Y2, stats[1], NN);
  k_fin<<<1, 128, 0, stream>>>(stats[1], gp[1], bep[1], ab[1], 128);
  // ---- layer 1 ----
  k_agg<true><<<agg_grid, 256, 0, stream>>>(Y2, ab[1], row_off, deg, col, X);
  k_gemm<4,8,false><<<gemm_grid, 256, 0, stream>>>(X, wt[2], nullptr, Y1, stats[2], NN);
  k_fin<<<1, 128, 0, stream>>>(stats[2], gp[2], bep[2], ab[2], 128);
  k_gemm<4,8,true><<<gemm_grid, 256, 0, stream>>>(Y1, wt[3], ab[2], Y2, stats[3], NN);
  k_fin<<<1, 128, 0, stream>>>(stats[3], gp[3], bep[3], ab[3], 128);
  // ---- layer 2 ----
  k_agg<true><<<agg_grid, 256, 0, stream>>>(Y2, ab[3], row_off, deg, col, X);
  k_gemm<4,4,false><<<gemm_grid, 256, 0, stream>>>(X, wt[4], nullptr, Y1, stats[4], NN);
  k_fin<<<1, 128, 0, stream>>>(stats[4], gp[4], bep[4], ab[4], 64);
  k_gemm<2,4,true><<<gemm_grid, 256, 0, stream>>>(Y1, wt[5], ab[4], Y2, stats[5], NN);
  k_fin<<<1, 128, 0, stream>>>(stats[5], gp[5], bep[5], ab[5], 64);
  k_final<<<(NN*32 + 255)/256, 256, 0, stream>>>(Y2, ab[5], (float*)d_out);
}

// Round 3
// 326.399 us; speedup vs baseline: 2.9485x; 1.2082x over previous
//
#include <hip/hip_runtime.h>

#define NN 50000
#define NE 600000
#define SREP 32

typedef __attribute__((ext_vector_type(8))) short short8;
typedef __attribute__((ext_vector_type(4))) float f32x4;

__device__ __forceinline__ float bf2f(unsigned short u){
  union { unsigned int i; float f; } c; c.i = ((unsigned int)u) << 16; return c.f;
}
__device__ __forceinline__ float lof(unsigned v){
  union { unsigned int i; float f; } c; c.i = v << 16; return c.f;
}
__device__ __forceinline__ float hif(unsigned v){
  union { unsigned int i; float f; } c; c.i = v & 0xFFFF0000u; return c.f;
}
__device__ __forceinline__ unsigned short f2b(float f){
  union { float f; unsigned int i; } c; c.f = f;
  unsigned int i = c.i;
  return (unsigned short)((i + 0x7FFFu + ((i >> 16) & 1u)) >> 16);
}

// ---------- fp32 -> bf16 convert ----------
__global__ void k_cvt_bf16(const float* __restrict__ in, unsigned short* __restrict__ out, int n4){
  int i = blockIdx.x*blockDim.x + threadIdx.x;
  if (i >= n4) return;
  float4 v = ((const float4*)in)[i];
  uint2 o;
  o.x = (unsigned)f2b(v.x) | ((unsigned)f2b(v.y) << 16);
  o.y = (unsigned)f2b(v.z) | ((unsigned)f2b(v.w) << 16);
  ((uint2*)out)[i] = o;
}

// ---------- CSR build ----------
__global__ void k_hist(const int* __restrict__ dst, int* __restrict__ deg, int e){
  int i = blockIdx.x*blockDim.x + threadIdx.x;
  if (i < e) atomicAdd(&deg[dst[i]], 1);
}

__global__ void k_offsets(const int* __restrict__ deg, int* __restrict__ row_off,
                          int* __restrict__ cur, int* __restrict__ total){
  __shared__ int ws[4];
  __shared__ int wbase[4];
  int tid = threadIdx.x, lane = tid & 63, wid = tid >> 6;
  int i = blockIdx.x*256 + tid;
  int v = (i < NN) ? deg[i] : 0;
  int x = v;
  #pragma unroll
  for (int o=1; o<64; o<<=1){
    int t = __shfl_up(x, o);
    if (lane >= o) x += t;
  }
  if (lane == 63) ws[wid] = x;
  __syncthreads();
  if (tid == 0){
    int s0=ws[0], s1=ws[1], s2=ws[2], s3=ws[3];
    int b = atomicAdd(total, s0+s1+s2+s3);
    wbase[0]=b; wbase[1]=b+s0; wbase[2]=b+s0+s1; wbase[3]=b+s0+s1+s2;
  }
  __syncthreads();
  if (i < NN){
    int excl = wbase[wid] + x - v;
    row_off[i] = excl;
    cur[i] = excl;
  }
}

__global__ void k_fill(const int* __restrict__ src, const int* __restrict__ dst,
                       int* __restrict__ cur, int* __restrict__ col, int e){
  int i = blockIdx.x*blockDim.x + threadIdx.x;
  if (i >= e) return;
  int d = dst[i];
  int pos = atomicAdd(&cur[d], 1);
  col[pos] = src[i];
}

// ---------- fused weight transpose+convert: 6 jobs, W[K][N] f32 -> WT[N][K] bf16 ----------
struct W6 { const float* w[6]; unsigned short* o[6]; };
__global__ void k_wconv(W6 jb){
  int i = blockIdx.x*256 + threadIdx.x;
  if (i >= 77824) return;
  int job, base, K, N;
  if (i < 65536){ job = i >> 14; base = job << 14; K = 128; N = 128; }
  else if (i < 73728){ job = 4; base = 65536; K = 128; N = 64; }
  else { job = 5; base = 73728; K = 64; N = 64; }
  int t = i - base;
  int k = t & (K-1);
  int n = t / K;
  jb.o[job][t] = f2b(jb.w[job][k*N + n]);
}

// ---------- aggregation: x = h + mean(h[neigh]); optional fused relu(bn) via ab ----------
template<bool APPLY>
__global__ __launch_bounds__(256) void k_agg(const unsigned short* __restrict__ H,
    const float* __restrict__ ab, const int* __restrict__ row_off,
    const int* __restrict__ deg, const int* __restrict__ col,
    unsigned short* __restrict__ X){
  int lane = threadIdx.x & 63;
  int node = blockIdx.x*4 + (threadIdx.x >> 6);
  if (node >= NN) return;
  const unsigned* hp = (const unsigned*)H;
  unsigned sv = hp[(size_t)node*64 + lane];
  int beg = row_off[node];
  int d = deg[node];
  float a0=0.f, b0=0.f, a1=0.f, b1=0.f;
  if (APPLY){
    float2 p0 = ((const float2*)ab)[2*lane];
    float2 p1 = ((const float2*)ab)[2*lane+1];
    a0=p0.x; b0=p0.y; a1=p1.x; b1=p1.y;
  }
  float s0=0.f, s1=0.f;
  for (int base=0; base<d; base+=64){
    int cnt = d - base; if (cnt > 64) cnt = 64;
    int cv = 0;
    if (lane < cnt) cv = col[beg + base + lane];
    int j = 0;
    for (; j+8 <= cnt; j += 8){
      int i0=__shfl(cv,j),   i1=__shfl(cv,j+1), i2=__shfl(cv,j+2), i3=__shfl(cv,j+3);
      int i4=__shfl(cv,j+4), i5=__shfl(cv,j+5), i6=__shfl(cv,j+6), i7=__shfl(cv,j+7);
      unsigned v0 = hp[(size_t)i0*64 + lane];
      unsigned v1 = hp[(size_t)i1*64 + lane];
      unsigned v2 = hp[(size_t)i2*64 + lane];
      unsigned v3 = hp[(size_t)i3*64 + lane];
      unsigned v4 = hp[(size_t)i4*64 + lane];
      unsigned v5 = hp[(size_t)i5*64 + lane];
      unsigned v6 = hp[(size_t)i6*64 + lane];
      unsigned v7 = hp[(size_t)i7*64 + lane];
      float x;
      x = lof(v0); if (APPLY) x = fmaxf(fmaf(x,a0,b0),0.f); s0 += x;
      x = hif(v0); if (APPLY) x = fmaxf(fmaf(x,a1,b1),0.f); s1 += x;
      x = lof(v1); if (APPLY) x = fmaxf(fmaf(x,a0,b0),0.f); s0 += x;
      x = hif(v1); if (APPLY) x = fmaxf(fmaf(x,a1,b1),0.f); s1 += x;
      x = lof(v2); if (APPLY) x = fmaxf(fmaf(x,a0,b0),0.f); s0 += x;
      x = hif(v2); if (APPLY) x = fmaxf(fmaf(x,a1,b1),0.f); s1 += x;
      x = lof(v3); if (APPLY) x = fmaxf(fmaf(x,a0,b0),0.f); s0 += x;
      x = hif(v3); if (APPLY) x = fmaxf(fmaf(x,a1,b1),0.f); s1 += x;
      x = lof(v4); if (APPLY) x = fmaxf(fmaf(x,a0,b0),0.f); s0 += x;
      x = hif(v4); if (APPLY) x = fmaxf(fmaf(x,a1,b1),0.f); s1 += x;
      x = lof(v5); if (APPLY) x = fmaxf(fmaf(x,a0,b0),0.f); s0 += x;
      x = hif(v5); if (APPLY) x = fmaxf(fmaf(x,a1,b1),0.f); s1 += x;
      x = lof(v6); if (APPLY) x = fmaxf(fmaf(x,a0,b0),0.f); s0 += x;
      x = hif(v6); if (APPLY) x = fmaxf(fmaf(x,a1,b1),0.f); s1 += x;
      x = lof(v7); if (APPLY) x = fmaxf(fmaf(x,a0,b0),0.f); s0 += x;
      x = hif(v7); if (APPLY) x = fmaxf(fmaf(x,a1,b1),0.f); s1 += x;
    }
    for (; j < cnt; ++j){
      int i0 = __shfl(cv, j);
      unsigned v0 = hp[(size_t)i0*64 + lane];
      float x = lof(v0); if (APPLY) x = fmaxf(fmaf(x,a0,b0),0.f); s0 += x;
      x = hif(v0); if (APPLY) x = fmaxf(fmaf(x,a1,b1),0.f); s1 += x;
    }
  }
  float h0 = lof(sv), h1 = hif(sv);
  if (APPLY){ h0 = fmaxf(fmaf(h0,a0,b0),0.f); h1 = fmaxf(fmaf(h1,a1,b1),0.f); }
  float inv = 1.f / (float)(d > 0 ? d : 1);
  float x0 = h0 + s0*inv;
  float x1 = h1 + s1*inv;
  ((unsigned*)X)[(size_t)node*64 + lane] = (unsigned)f2b(x0) | ((unsigned)f2b(x1) << 16);
}

// ---------- GEMM (bf16 MFMA) + fused BN stats epilogue; optional fused apply on A-load ----------
// Y[M][N] = act(A)[M][K] @ BT[N][K]^T   (bias dropped: it cancels inside BatchNorm)
// stats partials go to statsAcc[rep][2N], rep = blockIdx & (SREP-1) -> low atomic contention
template<int KSTEPS, int NTILES, bool APPLY>
__global__ __launch_bounds__(256) void k_gemm(const unsigned short* __restrict__ A,
    const unsigned short* __restrict__ BT, const float* __restrict__ abIn,
    unsigned short* __restrict__ Y, float* __restrict__ statsAcc, int M){
  constexpr int K = KSTEPS*32;
  constexpr int N = NTILES*16;
  __shared__ float red[2*N];
  int tid = threadIdx.x;
  int lane = tid & 63, wave = tid >> 6;
  int row0 = (blockIdx.x*4 + wave)*16;
  bool valid = (row0 < M);
  int r = lane & 15, g = lane >> 4;
  f32x4 acc[NTILES];
  #pragma unroll
  for (int t=0;t<NTILES;++t) acc[t] = (f32x4){0.f,0.f,0.f,0.f};
  if (valid){
    int arow = row0 + r;
    #pragma unroll
    for (int kk=0; kk<KSTEPS; ++kk){
      short8 af = *(const short8*)(A + (size_t)arow*K + kk*32 + g*8);
      if (APPLY){
        #pragma unroll
        for (int j=0;j<8;++j){
          float2 p = ((const float2*)abIn)[kk*32 + g*8 + j];
          float v = fmaxf(fmaf(bf2f((unsigned short)af[j]), p.x, p.y), 0.f);
          af[j] = (short)f2b(v);
        }
      }
      #pragma unroll
      for (int t=0;t<NTILES;++t){
        short8 bf = *(const short8*)(BT + (size_t)(t*16 + r)*K + kk*32 + g*8);
        acc[t] = __builtin_amdgcn_mfma_f32_16x16x32_bf16(af, bf, acc[t], 0, 0, 0);
      }
    }
  }
  for (int i=tid; i<2*N; i+=256) red[i] = 0.f;
  __syncthreads();
  if (valid){
    #pragma unroll
    for (int t=0;t<NTILES;++t){
      int c = t*16 + r;
      float ys = 0.f, yq = 0.f;
      #pragma unroll
      for (int j=0;j<4;++j){
        float y = acc[t][j];
        Y[(size_t)(row0 + g*4 + j)*N + c] = (unsigned short)f2b(y);
        ys += y; yq += y*y;
      }
      ys += __shfl_xor(ys, 16); ys += __shfl_xor(ys, 32);
      yq += __shfl_xor(yq, 16); yq += __shfl_xor(yq, 32);
      if (g == 0){
        atomicAdd(&red[c], ys);
        atomicAdd(&red[N+c], yq);
      }
    }
  }
  __syncthreads();
  float* dstAcc = statsAcc + (size_t)(blockIdx.x & (SREP-1)) * (2*N);
  for (int i=tid; i<2*N; i+=256) atomicAdd(&dstAcc[i], red[i]);
}

// ---------- finalize BN coefficients from replicated stats: a = g*rstd, b = be - mu*a ----------
__global__ void k_fin(const float* __restrict__ st, const float* __restrict__ gam,
                      const float* __restrict__ bet, float* __restrict__ ab, int N){
  int c = threadIdx.x;
  if (c >= N) return;
  float s=0.f, q=0.f;
  #pragma unroll 8
  for (int r=0;r<SREP;++r){
    s += st[r*2*N + c];
    q += st[r*2*N + N + c];
  }
  float mu = s * (1.f/(float)NN);
  float var = fmaxf(q * (1.f/(float)NN) - mu*mu, 0.f);
  float a = gam[c] * rsqrtf(var + 1e-5f);
  ((float2*)ab)[c] = make_float2(a, bet[c] - mu*a);
}

// ---------- final output: out = relu(a*y+b), f32 ----------
__global__ void k_final(const unsigned short* __restrict__ Y, const float* __restrict__ ab,
                        float* __restrict__ out){
  int i = blockIdx.x*256 + threadIdx.x;   // over NN*32 uints (2 bf16 each)
  if (i >= NN*32) return;
  unsigned v = ((const unsigned*)Y)[i];
  int c = (i & 31)*2;
  float2 p0 = ((const float2*)ab)[c], p1 = ((const float2*)ab)[c+1];
  float o0 = fmaxf(fmaf(lof(v), p0.x, p0.y), 0.f);
  float o1 = fmaxf(fmaf(hif(v), p1.x, p1.y), 0.f);
  ((float2*)out)[i] = make_float2(o0, o1);
}

extern "C" void kernel_launch(void* const* d_in, const int* in_sizes, int n_in,
                              void* d_out, int out_size, void* d_ws, size_t ws_size,
                              hipStream_t stream) {
  const float* features = (const float*)d_in[0];
  const int* src = (const int*)d_in[1];
  const int* dst = (const int*)d_in[2];
  const float *Wp[6], *gp[6], *bep[6];
  for (int l=0;l<3;++l){
    int base = 3 + 8*l;
    Wp[2*l]    = (const float*)d_in[base+0];
    gp[2*l]    = (const float*)d_in[base+2];
    bep[2*l]   = (const float*)d_in[base+3];
    Wp[2*l+1]  = (const float*)d_in[base+4];
    gp[2*l+1]  = (const float*)d_in[base+6];
    bep[2*l+1] = (const float*)d_in[base+7];
  }

  size_t off = 0;
  char* base = (char*)d_ws;
  auto carve = [&](size_t bytes)->char* {
    char* q = base + off; off += (bytes + 255) & ~(size_t)255; return q;
  };
  // zero-init region: deg + total + 6 replicated stats buffers (contiguous)
  int* deg     = (int*)carve((size_t)NN*4);
  int* total   = (int*)carve(4);
  float* stats[6];
  for (int i=0;i<6;++i) stats[i] = (float*)carve((size_t)SREP*256*4);
  size_t zbytes = (size_t)(base + off - (char*)deg);

  int* row_off = (int*)carve((size_t)NN*4);
  int* cur     = (int*)carve((size_t)NN*4);
  int* col     = (int*)carve((size_t)NE*4);
  unsigned short* wt[6];
  for (int i=0;i<6;++i) wt[i] = (unsigned short*)carve(128*128*2);
  float* ab[6];
  for (int i=0;i<6;++i) ab[i] = (float*)carve(128*2*4);
  unsigned short* H0 = (unsigned short*)carve((size_t)NN*128*2);
  unsigned short* X  = (unsigned short*)carve((size_t)NN*128*2);
  unsigned short* Y1 = (unsigned short*)carve((size_t)NN*128*2);
  unsigned short* Y2 = (unsigned short*)carve((size_t)NN*128*2);

  hipMemsetAsync(deg, 0, zbytes, stream);
  k_cvt_bf16<<<(NN*32 + 255)/256, 256, 0, stream>>>(features, H0, NN*32);
  k_hist<<<(NE+255)/256, 256, 0, stream>>>(dst, deg, NE);
  k_offsets<<<(NN+255)/256, 256, 0, stream>>>(deg, row_off, cur, total);
  k_fill<<<(NE+255)/256, 256, 0, stream>>>(src, dst, cur, col, NE);

  W6 jb;
  for (int i=0;i<6;++i){ jb.w[i] = Wp[i]; jb.o[i] = wt[i]; }
  k_wconv<<<(77824+255)/256, 256, 0, stream>>>(jb);

  const int agg_grid  = (NN + 3)/4;
  const int gemm_grid = (NN + 63)/64;

  // ---- layer 0 ----
  k_agg<false><<<agg_grid, 256, 0, stream>>>(H0, nullptr, row_off, deg, col, X);
  k_gemm<4,8,false><<<gemm_grid, 256, 0, stream>>>(X, wt[0], nullptr, Y1, stats[0], NN);
  k_fin<<<1, 128, 0, stream>>>(stats[0], gp[0], bep[0], ab[0], 128);
  k_gemm<4,8,true><<<gemm_grid, 256, 0, stream>>>(Y1, wt[1], ab[0], Y2, stats[1], NN);
  k_fin<<<1, 128, 0, stream>>>(stats[1], gp[1], bep[1], ab[1], 128);
  // ---- layer 1 ----
  k_agg<true><<<agg_grid, 256, 0, stream>>>(Y2, ab[1], row_off, deg, col, X);
  k_gemm<4,8,false><<<gemm_grid, 256, 0, stream>>>(X, wt[2], nullptr, Y1, stats[2], NN);
  k_fin<<<1, 128, 0, stream>>>(stats[2], gp[2], bep[2], ab[2], 128);
  k_gemm<4,8,true><<<gemm_grid, 256, 0, stream>>>(Y1, wt[3], ab[2], Y2, stats[3], NN);
  k_fin<<<1, 128, 0, stream>>>(stats[3], gp[3], bep[3], ab[3], 128);
  // ---- layer 2 ----
  k_agg<true><<<agg_grid, 256, 0, stream>>>(Y2, ab[3], row_off, deg, col, X);
  k_gemm<4,4,false><<<gemm_grid, 256, 0, stream>>>(X, wt[4], nullptr, Y1, stats[4], NN);
  k_fin<<<1, 64, 0, stream>>>(stats[4], gp[4], bep[4], ab[4], 64);
  k_gemm<2,4,true><<<gemm_grid, 256, 0, stream>>>(Y1, wt[5], ab[4], Y2, stats[5], NN);
  k_fin<<<1, 64, 0, stream>>>(stats[5], gp[5], bep[5], ab[5], 64);
  k_final<<<(NN*32 + 255)/256, 256, 0, stream>>>(Y2, ab[5], (float*)d_out);
}

// Round 5
// 308.869 us; speedup vs baseline: 3.1159x; 1.0568x over previous
//
#include <hip/hip_runtime.h>

#define NN 50000
#define NE 600000
#define SREP 32

typedef __attribute__((ext_vector_type(8))) short short8;
typedef __attribute__((ext_vector_type(4))) float f32x4;

__device__ __forceinline__ float bf2f(unsigned short u){
  union { unsigned int i; float f; } c; c.i = ((unsigned int)u) << 16; return c.f;
}
__device__ __forceinline__ float lof(unsigned v){
  union { unsigned int i; float f; } c; c.i = v << 16; return c.f;
}
__device__ __forceinline__ float hif(unsigned v){
  union { unsigned int i; float f; } c; c.i = v & 0xFFFF0000u; return c.f;
}
__device__ __forceinline__ unsigned short f2b(float f){
  union { float f; unsigned int i; } c; c.f = f;
  unsigned int i = c.i;
  return (unsigned short)((i + 0x7FFFu + ((i >> 16) & 1u)) >> 16);
}

// ---------- per-block BN coefficient computation from replicated stats ----------
template<int N>
__device__ __forceinline__ void compute_ab(const float* __restrict__ st,
    const float* __restrict__ gam, const float* __restrict__ bet, float2* absh){
  int tid = threadIdx.x;
  if (tid < N){
    float s = 0.f, q = 0.f;
    #pragma unroll
    for (int r = 0; r < SREP; ++r){
      s += st[r*2*N + tid];
      q += st[r*2*N + N + tid];
    }
    float mu = s * (1.f/(float)NN);
    float var = fmaxf(q * (1.f/(float)NN) - mu*mu, 0.f);
    float a = gam[tid] * rsqrtf(var + 1e-5f);
    absh[tid] = make_float2(a, bet[tid] - mu*a);
  }
  __syncthreads();
}

// ---------- fused preprocessing: cvt | hist | wconv ----------
struct W6 { const float* w[6]; unsigned short* o[6]; };
__global__ __launch_bounds__(256) void k_pre(const float* __restrict__ features,
    unsigned short* __restrict__ H0, const int* __restrict__ dst,
    int* __restrict__ deg, W6 jb){
  int b = blockIdx.x, tid = threadIdx.x;
  if (b < 6250){                       // cvt: NN*128 floats as float4 -> bf16x4
    int i = b*256 + tid;               // i < NN*32 exactly
    float4 v = ((const float4*)features)[i];
    uint2 o;
    o.x = (unsigned)f2b(v.x) | ((unsigned)f2b(v.y) << 16);
    o.y = (unsigned)f2b(v.z) | ((unsigned)f2b(v.w) << 16);
    ((uint2*)H0)[i] = o;
  } else if (b < 6250 + 2344){         // hist
    int i = (b - 6250)*256 + tid;
    if (i < NE) atomicAdd(&deg[dst[i]], 1);
  } else {                             // weight transpose+convert, 6 jobs
    int i = (b - 8594)*256 + tid;
    if (i < 77824){
      int job, base, K, N;
      if (i < 65536){ job = i >> 14; base = job << 14; K = 128; N = 128; }
      else if (i < 73728){ job = 4; base = 65536; K = 128; N = 64; }
      else { job = 5; base = 73728; K = 64; N = 64; }
      int t = i - base;
      int k = t & (K-1);
      int n = t / K;
      jb.o[job][t] = f2b(jb.w[job][k*N + n]);
    }
  }
}

// ---------- CSR offsets (block-local scan + atomic base) ----------
__global__ void k_offsets(const int* __restrict__ deg, int* __restrict__ row_off,
                          int* __restrict__ cur, int* __restrict__ total){
  __shared__ int ws[4];
  __shared__ int wbase[4];
  int tid = threadIdx.x, lane = tid & 63, wid = tid >> 6;
  int i = blockIdx.x*256 + tid;
  int v = (i < NN) ? deg[i] : 0;
  int x = v;
  #pragma unroll
  for (int o = 1; o < 64; o <<= 1){
    int t = __shfl_up(x, o);
    if (lane >= o) x += t;
  }
  if (lane == 63) ws[wid] = x;
  __syncthreads();
  if (tid == 0){
    int s0 = ws[0], s1 = ws[1], s2 = ws[2], s3 = ws[3];
    int b = atomicAdd(total, s0+s1+s2+s3);
    wbase[0] = b; wbase[1] = b+s0; wbase[2] = b+s0+s1; wbase[3] = b+s0+s1+s2;
  }
  __syncthreads();
  if (i < NN){
    int excl = wbase[wid] + x - v;
    row_off[i] = excl;
    cur[i] = excl;
  }
}

__global__ void k_fill(const int* __restrict__ src, const int* __restrict__ dst,
                       int* __restrict__ cur, int* __restrict__ col, int e){
  int i = blockIdx.x*blockDim.x + threadIdx.x;
  if (i >= e) return;
  int d = dst[i];
  int pos = atomicAdd(&cur[d], 1);
  col[pos] = src[i];
}

// ---------- aggregation: x = act(h) + mean(act(h[neigh])) ----------
// quad scheme: 16 lanes x uint4 per row, 4 rows concurrent per wave
template<bool APPLY>
__global__ __launch_bounds__(256) void k_agg(const unsigned short* __restrict__ H,
    const float* __restrict__ st, const float* __restrict__ gam,
    const float* __restrict__ bet, const int* __restrict__ row_off,
    const int* __restrict__ deg, const int* __restrict__ col,
    unsigned short* __restrict__ X){
  __shared__ float2 absh[128];
  if (APPLY) compute_ab<128>(st, gam, bet, absh);
  int lane = threadIdx.x & 63;
  int wave = threadIdx.x >> 6;
  int p = lane & 15, q = lane >> 4;
  float ac[8], bc[8];
  if (APPLY){
    #pragma unroll
    for (int e = 0; e < 8; ++e){ float2 t = absh[p*8 + e]; ac[e] = t.x; bc[e] = t.y; }
  }
  const uint4* hp4 = (const uint4*)H;
  for (int node = blockIdx.x*4 + wave; node < NN; node += gridDim.x*4){
    int beg = row_off[node];
    int d = deg[node];
    float s[8];
    #pragma unroll
    for (int e = 0; e < 8; ++e) s[e] = 0.f;
    auto ACC = [&](uint4 v){
      float x;
      x = lof(v.x); if (APPLY) x = fmaxf(fmaf(x,ac[0],bc[0]),0.f); s[0] += x;
      x = hif(v.x); if (APPLY) x = fmaxf(fmaf(x,ac[1],bc[1]),0.f); s[1] += x;
      x = lof(v.y); if (APPLY) x = fmaxf(fmaf(x,ac[2],bc[2]),0.f); s[2] += x;
      x = hif(v.y); if (APPLY) x = fmaxf(fmaf(x,ac[3],bc[3]),0.f); s[3] += x;
      x = lof(v.z); if (APPLY) x = fmaxf(fmaf(x,ac[4],bc[4]),0.f); s[4] += x;
      x = hif(v.z); if (APPLY) x = fmaxf(fmaf(x,ac[5],bc[5]),0.f); s[5] += x;
      x = lof(v.w); if (APPLY) x = fmaxf(fmaf(x,ac[6],bc[6]),0.f); s[6] += x;
      x = hif(v.w); if (APPLY) x = fmaxf(fmaf(x,ac[7],bc[7]),0.f); s[7] += x;
    };
    for (int base = 0; base < d; base += 64){
      int cnt = d - base; if (cnt > 64) cnt = 64;
      int cv = (lane < cnt) ? col[beg + base + lane] : 0;
      int full = cnt >> 2;
      int rr = 0;
      for (; rr + 2 <= full; rr += 2){
        int i0 = __shfl(cv, rr*4 + q);
        int i1 = __shfl(cv, rr*4 + 4 + q);
        uint4 v0 = hp4[(size_t)i0*16 + p];
        uint4 v1 = hp4[(size_t)i1*16 + p];
        ACC(v0); ACC(v1);
      }
      if (rr < full){
        int i0 = __shfl(cv, rr*4 + q);
        uint4 v0 = hp4[(size_t)i0*16 + p];
        ACC(v0);
      }
      int rem = cnt & 3;
      if (rem){
        // shuffle executed wave-uniformly (all 64 lanes active -> all sources
        // active); ds_bpermute from an inactive source lane returns 0, which
        // was the round-4 bug. Clamp index into the valid range instead.
        int i0 = __shfl(cv, full*4 + (q < rem ? q : 0));
        if (q < rem){
          uint4 v0 = hp4[(size_t)i0*16 + p];
          ACC(v0);
        }
      }
    }
    #pragma unroll
    for (int e = 0; e < 8; ++e){
      s[e] += __shfl_xor(s[e], 16);
      s[e] += __shfl_xor(s[e], 32);
    }
    if (q == 0){
      uint4 hv = hp4[(size_t)node*16 + p];
      float inv = 1.f / (float)(d > 0 ? d : 1);
      float h[8] = {lof(hv.x),hif(hv.x),lof(hv.y),hif(hv.y),
                    lof(hv.z),hif(hv.z),lof(hv.w),hif(hv.w)};
      unsigned w[4];
      #pragma unroll
      for (int u = 0; u < 4; ++u){
        float x0 = h[2*u], x1 = h[2*u+1];
        if (APPLY){
          x0 = fmaxf(fmaf(x0,ac[2*u],bc[2*u]),0.f);
          x1 = fmaxf(fmaf(x1,ac[2*u+1],bc[2*u+1]),0.f);
        }
        x0 += s[2*u]*inv;
        x1 += s[2*u+1]*inv;
        w[u] = (unsigned)f2b(x0) | ((unsigned)f2b(x1) << 16);
      }
      ((uint4*)X)[(size_t)node*16 + p] = make_uint4(w[0], w[1], w[2], w[3]);
    }
  }
}

// ---------- GEMM (bf16 MFMA) + fused BN stats epilogue + fused BN apply on A ----------
template<int KSTEPS, int NTILES, bool APPLY>
__global__ __launch_bounds__(256) void k_gemm(const unsigned short* __restrict__ A,
    const unsigned short* __restrict__ BT,
    const float* __restrict__ stIn, const float* __restrict__ gam,
    const float* __restrict__ bet,
    unsigned short* __restrict__ Y, float* __restrict__ statsAcc, int M){
  constexpr int K = KSTEPS*32;
  constexpr int N = NTILES*16;
  __shared__ float red[2*N];
  __shared__ float2 absh[K];
  if (APPLY) compute_ab<K>(stIn, gam, bet, absh);
  int tid = threadIdx.x;
  int lane = tid & 63, wave = tid >> 6;
  int row0 = (blockIdx.x*4 + wave)*16;
  bool valid = (row0 < M);
  int r = lane & 15, g = lane >> 4;
  f32x4 acc[NTILES];
  #pragma unroll
  for (int t = 0; t < NTILES; ++t) acc[t] = (f32x4){0.f,0.f,0.f,0.f};
  if (valid){
    int arow = row0 + r;
    short8 af[KSTEPS];
    #pragma unroll
    for (int kk = 0; kk < KSTEPS; ++kk)
      af[kk] = *(const short8*)(A + (size_t)arow*K + kk*32 + g*8);
    if (APPLY){
      #pragma unroll
      for (int kk = 0; kk < KSTEPS; ++kk){
        #pragma unroll
        for (int j = 0; j < 8; ++j){
          float2 pab = absh[kk*32 + g*8 + j];
          float v = fmaxf(fmaf(bf2f((unsigned short)af[kk][j]), pab.x, pab.y), 0.f);
          af[kk][j] = (short)f2b(v);
        }
      }
    }
    #pragma unroll
    for (int kk = 0; kk < KSTEPS; ++kk){
      #pragma unroll
      for (int t = 0; t < NTILES; ++t){
        short8 bf = *(const short8*)(BT + (size_t)(t*16 + r)*K + kk*32 + g*8);
        acc[t] = __builtin_amdgcn_mfma_f32_16x16x32_bf16(af[kk], bf, acc[t], 0, 0, 0);
      }
    }
  }
  for (int i = tid; i < 2*N; i += 256) red[i] = 0.f;
  __syncthreads();
  if (valid){
    #pragma unroll
    for (int t = 0; t < NTILES; ++t){
      int c = t*16 + r;
      float ys = 0.f, yq = 0.f;
      #pragma unroll
      for (int j = 0; j < 4; ++j){
        float y = acc[t][j];
        Y[(size_t)(row0 + g*4 + j)*N + c] = (unsigned short)f2b(y);
        ys += y; yq += y*y;
      }
      ys += __shfl_xor(ys, 16); ys += __shfl_xor(ys, 32);
      yq += __shfl_xor(yq, 16); yq += __shfl_xor(yq, 32);
      if (g == 0){
        atomicAdd(&red[c], ys);
        atomicAdd(&red[N+c], yq);
      }
    }
  }
  __syncthreads();
  float* dstAcc = statsAcc + (size_t)(blockIdx.x & (SREP-1)) * (2*N);
  for (int i = tid; i < 2*N; i += 256) atomicAdd(&dstAcc[i], red[i]);
}

// ---------- final output: out = relu(a*y+b), f32, grid-stride ----------
__global__ __launch_bounds__(256) void k_final(const unsigned short* __restrict__ Y,
    const float* __restrict__ st, const float* __restrict__ gam,
    const float* __restrict__ bet, float* __restrict__ out){
  __shared__ float2 absh[64];
  compute_ab<64>(st, gam, bet, absh);
  for (int i = blockIdx.x*256 + threadIdx.x; i < NN*32; i += gridDim.x*256){
    unsigned v = ((const unsigned*)Y)[i];
    int c = (i & 31)*2;
    float2 p0 = absh[c], p1 = absh[c+1];
    float o0 = fmaxf(fmaf(lof(v), p0.x, p0.y), 0.f);
    float o1 = fmaxf(fmaf(hif(v), p1.x, p1.y), 0.f);
    ((float2*)out)[i] = make_float2(o0, o1);
  }
}

extern "C" void kernel_launch(void* const* d_in, const int* in_sizes, int n_in,
                              void* d_out, int out_size, void* d_ws, size_t ws_size,
                              hipStream_t stream) {
  const float* features = (const float*)d_in[0];
  const int* src = (const int*)d_in[1];
  const int* dst = (const int*)d_in[2];
  const float *Wp[6], *gp[6], *bep[6];
  for (int l = 0; l < 3; ++l){
    int base = 3 + 8*l;
    Wp[2*l]    = (const float*)d_in[base+0];
    gp[2*l]    = (const float*)d_in[base+2];
    bep[2*l]   = (const float*)d_in[base+3];
    Wp[2*l+1]  = (const float*)d_in[base+4];
    gp[2*l+1]  = (const float*)d_in[base+6];
    bep[2*l+1] = (const float*)d_in[base+7];
  }

  size_t off = 0;
  char* base = (char*)d_ws;
  auto carve = [&](size_t bytes)->char* {
    char* q = base + off; off += (bytes + 255) & ~(size_t)255; return q;
  };
  // zero-init region: deg + total + 6 replicated stats buffers (contiguous)
  int* deg   = (int*)carve((size_t)NN*4);
  int* total = (int*)carve(4);
  float* stats[6];
  for (int i = 0; i < 6; ++i) stats[i] = (float*)carve((size_t)SREP*256*4);
  size_t zbytes = (size_t)(base + off - (char*)deg);

  int* row_off = (int*)carve((size_t)NN*4);
  int* cur     = (int*)carve((size_t)NN*4);
  int* col     = (int*)carve((size_t)NE*4);
  unsigned short* wt[6];
  for (int i = 0; i < 6; ++i) wt[i] = (unsigned short*)carve(128*128*2);
  unsigned short* H0 = (unsigned short*)carve((size_t)NN*128*2);
  unsigned short* X  = (unsigned short*)carve((size_t)NN*128*2);
  unsigned short* Y1 = (unsigned short*)carve((size_t)NN*128*2);
  unsigned short* Y2 = (unsigned short*)carve((size_t)NN*128*2);

  hipMemsetAsync(deg, 0, zbytes, stream);

  W6 jb;
  for (int i = 0; i < 6; ++i){ jb.w[i] = Wp[i]; jb.o[i] = wt[i]; }
  k_pre<<<8898, 256, 0, stream>>>(features, H0, dst, deg, jb);
  k_offsets<<<(NN+255)/256, 256, 0, stream>>>(deg, row_off, cur, total);
  k_fill<<<(NE+255)/256, 256, 0, stream>>>(src, dst, cur, col, NE);

  const int agg_grid  = 3125;
  const int gemm_grid = (NN + 63)/64;

  // ---- layer 0 ----
  k_agg<false><<<agg_grid, 256, 0, stream>>>(H0, nullptr, nullptr, nullptr, row_off, deg, col, X);
  k_gemm<4,8,false><<<gemm_grid, 256, 0, stream>>>(X, wt[0], nullptr, nullptr, nullptr, Y1, stats[0], NN);
  k_gemm<4,8,true ><<<gemm_grid, 256, 0, stream>>>(Y1, wt[1], stats[0], gp[0], bep[0], Y2, stats[1], NN);
  // ---- layer 1 ----
  k_agg<true ><<<agg_grid, 256, 0, stream>>>(Y2, stats[1], gp[1], bep[1], row_off, deg, col, X);
  k_gemm<4,8,false><<<gemm_grid, 256, 0, stream>>>(X, wt[2], nullptr, nullptr, nullptr, Y1, stats[2], NN);
  k_gemm<4,8,true ><<<gemm_grid, 256, 0, stream>>>(Y1, wt[3], stats[2], gp[2], bep[2], Y2, stats[3], NN);
  // ---- layer 2 ----
  k_agg<true ><<<agg_grid, 256, 0, stream>>>(Y2, stats[3], gp[3], bep[3], row_off, deg, col, X);
  k_gemm<4,4,false><<<gemm_grid, 256, 0, stream>>>(X, wt[4], nullptr, nullptr, nullptr, Y1, stats[4], NN);
  k_gemm<2,4,true ><<<gemm_grid, 256, 0, stream>>>(Y1, wt[5], stats[4], gp[4], bep[4], Y2, stats[5], NN);
  k_final<<<782, 256, 0, stream>>>(Y2, stats[5], gp[5], bep[5], (float*)d_out);
}

// Round 7
// 302.015 us; speedup vs baseline: 3.1866x; 1.0227x over previous
//
#include <hip/hip_runtime.h>

#define NN 50000
#define NE 600000
#define SREP 32

typedef __attribute__((ext_vector_type(8))) short short8;
typedef __attribute__((ext_vector_type(4))) float f32x4;

__device__ __forceinline__ float bf2f(unsigned short u){
  union { unsigned int i; float f; } c; c.i = ((unsigned int)u) << 16; return c.f;
}
__device__ __forceinline__ float lof(unsigned v){
  union { unsigned int i; float f; } c; c.i = v << 16; return c.f;
}
__device__ __forceinline__ float hif(unsigned v){
  union { unsigned int i; float f; } c; c.i = v & 0xFFFF0000u; return c.f;
}
__device__ __forceinline__ unsigned short f2b(float f){
  union { float f; unsigned int i; } c; c.f = f;
  unsigned int i = c.i;
  return (unsigned short)((i + 0x7FFFu + ((i >> 16) & 1u)) >> 16);
}

// ---------- per-block BN coefficient computation from replicated stats ----------
template<int N>
__device__ __forceinline__ void compute_ab(const float* __restrict__ st,
    const float* __restrict__ gam, const float* __restrict__ bet, float2* absh){
  int tid = threadIdx.x;
  if (tid < N){
    float s = 0.f, q = 0.f;
    #pragma unroll
    for (int r = 0; r < SREP; ++r){
      s += st[r*2*N + tid];
      q += st[r*2*N + N + tid];
    }
    float mu = s * (1.f/(float)NN);
    float var = fmaxf(q * (1.f/(float)NN) - mu*mu, 0.f);
    float a = gam[tid] * rsqrtf(var + 1e-5f);
    absh[tid] = make_float2(a, bet[tid] - mu*a);
  }
}

// ---------- fused preprocessing: cvt | hist | wconv | zero dummy rows ----------
struct W6 { const float* w[6]; unsigned short* o[6]; };
__global__ __launch_bounds__(256) void k_pre(const float* __restrict__ features,
    unsigned short* __restrict__ H0, unsigned short* __restrict__ X,
    unsigned short* __restrict__ Y1, unsigned short* __restrict__ Y2,
    const int* __restrict__ dst, int* __restrict__ deg, W6 jb){
  int b = blockIdx.x, tid = threadIdx.x;
  if (b < 6250){                       // cvt: NN*128 floats as float4 -> bf16x4
    int i = b*256 + tid;               // i < NN*32 exactly
    float4 v = ((const float4*)features)[i];
    uint2 o;
    o.x = (unsigned)f2b(v.x) | ((unsigned)f2b(v.y) << 16);
    o.y = (unsigned)f2b(v.z) | ((unsigned)f2b(v.w) << 16);
    ((uint2*)H0)[i] = o;
  } else if (b < 6250 + 2344){         // hist
    int i = (b - 6250)*256 + tid;
    if (i < NE) atomicAdd(&deg[dst[i]], 1);
  } else if (b < 6250 + 2344 + 304){   // weight transpose+convert, 6 jobs
    int i = (b - 8594)*256 + tid;
    if (i < 77824){
      int job, base, K, N;
      if (i < 65536){ job = i >> 14; base = job << 14; K = 128; N = 128; }
      else if (i < 73728){ job = 4; base = 65536; K = 128; N = 64; }
      else { job = 5; base = 73728; K = 64; N = 64; }
      int t = i - base;
      int k = t & (K-1);
      int n = t / K;
      jb.o[job][t] = f2b(jb.w[job][k*N + n]);
    }
  } else {                             // zero dummy row NN of each feature table
    if (tid < 64){
      unsigned short* bufs[4] = {H0, X, Y1, Y2};
      unsigned short* bp = bufs[tid >> 4];
      ((uint4*)bp)[(size_t)NN*16 + (tid & 15)] = make_uint4(0,0,0,0);
    }
  }
}

// ---------- CSR offsets (block-local scan over PADDED degrees + pad-slot fill) ----------
__global__ void k_offsets(const int* __restrict__ deg, int* __restrict__ row_off,
                          int* __restrict__ cur, int* __restrict__ col,
                          int* __restrict__ total){
  __shared__ int ws[4];
  __shared__ int wbase[4];
  int tid = threadIdx.x, lane = tid & 63, wid = tid >> 6;
  int i = blockIdx.x*256 + tid;
  int v = (i < NN) ? deg[i] : 0;
  int vp = (v + 3) & ~3;               // padded degree
  int x = vp;
  #pragma unroll
  for (int o = 1; o < 64; o <<= 1){
    int t = __shfl_up(x, o);
    if (lane >= o) x += t;
  }
  if (lane == 63) ws[wid] = x;
  __syncthreads();
  if (tid == 0){
    int s0 = ws[0], s1 = ws[1], s2 = ws[2], s3 = ws[3];
    int b = atomicAdd(total, s0+s1+s2+s3);
    wbase[0] = b; wbase[1] = b+s0; wbase[2] = b+s0+s1; wbase[3] = b+s0+s1+s2;
  }
  __syncthreads();
  if (i < NN){
    int excl = wbase[wid] + x - vp;
    row_off[i] = excl;
    cur[i] = excl;
    for (int t = v; t < vp; ++t) col[excl + t] = NN;   // pad -> zero dummy node
  }
}

__global__ void k_fill(const int* __restrict__ src, const int* __restrict__ dst,
                       int* __restrict__ cur, int* __restrict__ col, int e){
  int i = blockIdx.x*blockDim.x + threadIdx.x;
  if (i >= e) return;
  int d = dst[i];
  int pos = atomicAdd(&cur[d], 1);
  col[pos] = src[i];
}

// ---------- aggregation: x = act(h) + mean(act(h[neigh])) ----------
// quad scheme: 16 lanes x uint4 per row, 4 rows concurrent per wave, padded CSR.
// Pad edges gather the zero dummy row; with APPLY each contributes exactly
// relu(b_c) per column, subtracted analytically after the reduction.
template<bool APPLY>
__global__ __launch_bounds__(256) void k_agg(const unsigned short* __restrict__ H,
    const float* __restrict__ st, const float* __restrict__ gam,
    const float* __restrict__ bet, const int* __restrict__ row_off,
    const int* __restrict__ deg, const int* __restrict__ col,
    unsigned short* __restrict__ X){
  __shared__ float2 absh[128];
  if (APPLY){ compute_ab<128>(st, gam, bet, absh); __syncthreads(); }
  int lane = threadIdx.x & 63;
  int wave = threadIdx.x >> 6;
  int p = lane & 15, q = lane >> 4;
  float ac[8], bc[8];
  if (APPLY){
    #pragma unroll
    for (int e = 0; e < 8; ++e){ float2 t = absh[p*8 + e]; ac[e] = t.x; bc[e] = t.y; }
  }
  const uint4* hp4 = (const uint4*)H;
  for (int node = blockIdx.x*4 + wave; node < NN; node += gridDim.x*4){
    int beg = row_off[node];
    int d = deg[node];
    int dp = (d + 3) & ~3;
    float s[8];
    #pragma unroll
    for (int e = 0; e < 8; ++e) s[e] = 0.f;
    auto ACC = [&](uint4 v){
      float x;
      x = lof(v.x); if (APPLY) x = fmaxf(fmaf(x,ac[0],bc[0]),0.f); s[0] += x;
      x = hif(v.x); if (APPLY) x = fmaxf(fmaf(x,ac[1],bc[1]),0.f); s[1] += x;
      x = lof(v.y); if (APPLY) x = fmaxf(fmaf(x,ac[2],bc[2]),0.f); s[2] += x;
      x = hif(v.y); if (APPLY) x = fmaxf(fmaf(x,ac[3],bc[3]),0.f); s[3] += x;
      x = lof(v.z); if (APPLY) x = fmaxf(fmaf(x,ac[4],bc[4]),0.f); s[4] += x;
      x = hif(v.z); if (APPLY) x = fmaxf(fmaf(x,ac[5],bc[5]),0.f); s[5] += x;
      x = lof(v.w); if (APPLY) x = fmaxf(fmaf(x,ac[6],bc[6]),0.f); s[6] += x;
      x = hif(v.w); if (APPLY) x = fmaxf(fmaf(x,ac[7],bc[7]),0.f); s[7] += x;
    };
    for (int base = 0; base < dp; base += 64){
      int cnt = dp - base; if (cnt > 64) cnt = 64;   // multiple of 4
      int cv = (lane < cnt) ? col[beg + base + lane] : 0;
      int full = cnt >> 2;
      int rr = 0;
      for (; rr + 4 <= full; rr += 4){
        int i0 = __shfl(cv, rr*4 + q);
        int i1 = __shfl(cv, rr*4 + 4 + q);
        int i2 = __shfl(cv, rr*4 + 8 + q);
        int i3 = __shfl(cv, rr*4 + 12 + q);
        uint4 v0 = hp4[(size_t)i0*16 + p];
        uint4 v1 = hp4[(size_t)i1*16 + p];
        uint4 v2 = hp4[(size_t)i2*16 + p];
        uint4 v3 = hp4[(size_t)i3*16 + p];
        ACC(v0); ACC(v1); ACC(v2); ACC(v3);
      }
      for (; rr < full; ++rr){
        int i0 = __shfl(cv, rr*4 + q);
        uint4 v0 = hp4[(size_t)i0*16 + p];
        ACC(v0);
      }
    }
    #pragma unroll
    for (int e = 0; e < 8; ++e){
      s[e] += __shfl_xor(s[e], 16);
      s[e] += __shfl_xor(s[e], 32);
    }
    if (q == 0){
      uint4 hv = hp4[(size_t)node*16 + p];
      float inv = 1.f / (float)(d > 0 ? d : 1);
      float npad = (float)(dp - d);
      float h[8] = {lof(hv.x),hif(hv.x),lof(hv.y),hif(hv.y),
                    lof(hv.z),hif(hv.z),lof(hv.w),hif(hv.w)};
      unsigned w[4];
      #pragma unroll
      for (int u = 0; u < 4; ++u){
        float x0 = h[2*u], x1 = h[2*u+1];
        float s0 = s[2*u], s1 = s[2*u+1];
        if (APPLY){
          x0 = fmaxf(fmaf(x0,ac[2*u],bc[2*u]),0.f);
          x1 = fmaxf(fmaf(x1,ac[2*u+1],bc[2*u+1]),0.f);
          s0 -= npad * fmaxf(bc[2*u], 0.f);     // remove pad-edge relu(b) terms
          s1 -= npad * fmaxf(bc[2*u+1], 0.f);
        }
        x0 += s0*inv;
        x1 += s1*inv;
        w[u] = (unsigned)f2b(x0) | ((unsigned)f2b(x1) << 16);
      }
      ((uint4*)X)[(size_t)node*16 + p] = make_uint4(w[0], w[1], w[2], w[3]);
    }
  }
}

// ---------- GEMM: B fully in registers, grid-stride over 16-row tiles ----------
// Y[NN][N] = act(A)[NN][K] @ BT[N][K]^T, fused BN stats + optional BN apply on A
template<int KSTEPS, int NTILES, bool APPLY>
__global__ __launch_bounds__(256) void k_gemm(const unsigned short* __restrict__ A,
    const unsigned short* __restrict__ BT,
    const float* __restrict__ stIn, const float* __restrict__ gam,
    const float* __restrict__ bet,
    unsigned short* __restrict__ Y, float* __restrict__ statsAcc){
  constexpr int K = KSTEPS*32;
  constexpr int N = NTILES*16;
  constexpr int TILES = NN/16;         // 3125 exactly
  __shared__ float red[2*N];
  __shared__ float2 absh[K];
  if (APPLY) compute_ab<K>(stIn, gam, bet, absh);
  int tid = threadIdx.x;
  int lane = tid & 63, wave = tid >> 6;
  int r = lane & 15, g = lane >> 4;
  for (int i = tid; i < 2*N; i += 256) red[i] = 0.f;
  __syncthreads();
  // preload all of B into registers
  short8 bf[KSTEPS][NTILES];
  #pragma unroll
  for (int kk = 0; kk < KSTEPS; ++kk)
    #pragma unroll
    for (int t = 0; t < NTILES; ++t)
      bf[kk][t] = *(const short8*)(BT + (size_t)(t*16 + r)*K + kk*32 + g*8);
  float ysum[NTILES], yqsum[NTILES];
  #pragma unroll
  for (int t = 0; t < NTILES; ++t){ ysum[t] = 0.f; yqsum[t] = 0.f; }

  for (int tile = blockIdx.x*4 + wave; tile < TILES; tile += gridDim.x*4){
    int arow = tile*16 + r;
    f32x4 acc[NTILES];
    #pragma unroll
    for (int t = 0; t < NTILES; ++t) acc[t] = (f32x4){0.f,0.f,0.f,0.f};
    #pragma unroll
    for (int kk = 0; kk < KSTEPS; ++kk){
      short8 af = *(const short8*)(A + (size_t)arow*K + kk*32 + g*8);
      if (APPLY){
        #pragma unroll
        for (int j = 0; j < 8; ++j){
          float2 pab = absh[kk*32 + g*8 + j];
          float v = fmaxf(fmaf(bf2f((unsigned short)af[j]), pab.x, pab.y), 0.f);
          af[j] = (short)f2b(v);
        }
      }
      #pragma unroll
      for (int t = 0; t < NTILES; ++t)
        acc[t] = __builtin_amdgcn_mfma_f32_16x16x32_bf16(af, bf[kk][t], acc[t], 0, 0, 0);
    }
    #pragma unroll
    for (int t = 0; t < NTILES; ++t){
      int c = t*16 + r;
      float ys = 0.f, yq = 0.f;
      #pragma unroll
      for (int j = 0; j < 4; ++j){
        float y = acc[t][j];
        Y[(size_t)(tile*16 + g*4 + j)*N + c] = (unsigned short)f2b(y);
        ys += y; yq += y*y;
      }
      ysum[t] += ys; yqsum[t] += yq;
    }
  }
  // reduce stats: fold k-groups, then block-level LDS, then one global pass
  #pragma unroll
  for (int t = 0; t < NTILES; ++t){
    ysum[t]  += __shfl_xor(ysum[t], 16);  ysum[t]  += __shfl_xor(ysum[t], 32);
    yqsum[t] += __shfl_xor(yqsum[t], 16); yqsum[t] += __shfl_xor(yqsum[t], 32);
  }
  if (g == 0){
    #pragma unroll
    for (int t = 0; t < NTILES; ++t){
      atomicAdd(&red[t*16 + r], ysum[t]);
      atomicAdd(&red[N + t*16 + r], yqsum[t]);
    }
  }
  __syncthreads();
  float* dstAcc = statsAcc + (size_t)(blockIdx.x & (SREP-1)) * (2*N);
  for (int i = tid; i < 2*N; i += 256) atomicAdd(&dstAcc[i], red[i]);
}

// ---------- final output: out = relu(a*y+b), f32, grid-stride ----------
__global__ __launch_bounds__(256) void k_final(const unsigned short* __restrict__ Y,
    const float* __restrict__ st, const float* __restrict__ gam,
    const float* __restrict__ bet, float* __restrict__ out){
  __shared__ float2 absh[64];
  compute_ab<64>(st, gam, bet, absh);
  __syncthreads();
  for (int i = blockIdx.x*256 + threadIdx.x; i < NN*32; i += gridDim.x*256){
    unsigned v = ((const unsigned*)Y)[i];
    int c = (i & 31)*2;
    float2 p0 = absh[c], p1 = absh[c+1];
    float o0 = fmaxf(fmaf(lof(v), p0.x, p0.y), 0.f);
    float o1 = fmaxf(fmaf(hif(v), p1.x, p1.y), 0.f);
    ((float2*)out)[i] = make_float2(o0, o1);
  }
}

extern "C" void kernel_launch(void* const* d_in, const int* in_sizes, int n_in,
                              void* d_out, int out_size, void* d_ws, size_t ws_size,
                              hipStream_t stream) {
  const float* features = (const float*)d_in[0];
  const int* src = (const int*)d_in[1];
  const int* dst = (const int*)d_in[2];
  const float *Wp[6], *gp[6], *bep[6];
  for (int l = 0; l < 3; ++l){
    int base = 3 + 8*l;
    Wp[2*l]    = (const float*)d_in[base+0];
    gp[2*l]    = (const float*)d_in[base+2];
    bep[2*l]   = (const float*)d_in[base+3];
    Wp[2*l+1]  = (const float*)d_in[base+4];
    gp[2*l+1]  = (const float*)d_in[base+6];
    bep[2*l+1] = (const float*)d_in[base+7];
  }

  size_t off = 0;
  char* base = (char*)d_ws;
  auto carve = [&](size_t bytes)->char* {
    char* q = base + off; off += (bytes + 255) & ~(size_t)255; return q;
  };
  // zero-init region: deg + total + 6 replicated stats buffers (contiguous)
  int* deg   = (int*)carve((size_t)NN*4);
  int* total = (int*)carve(4);
  float* stats[6];
  for (int i = 0; i < 6; ++i) stats[i] = (float*)carve((size_t)SREP*256*4);
  size_t zbytes = (size_t)(base + off - (char*)deg);

  int* row_off = (int*)carve((size_t)NN*4);
  int* cur     = (int*)carve((size_t)NN*4);
  int* col     = (int*)carve((size_t)(NE + 3*NN)*4);   // padded CSR
  unsigned short* wt[6];
  for (int i = 0; i < 6; ++i) wt[i] = (unsigned short*)carve(128*128*2);
  unsigned short* H0 = (unsigned short*)carve((size_t)(NN+1)*128*2);
  unsigned short* X  = (unsigned short*)carve((size_t)(NN+1)*128*2);
  unsigned short* Y1 = (unsigned short*)carve((size_t)(NN+1)*128*2);
  unsigned short* Y2 = (unsigned short*)carve((size_t)(NN+1)*128*2);

  hipMemsetAsync(deg, 0, zbytes, stream);

  W6 jb;
  for (int i = 0; i < 6; ++i){ jb.w[i] = Wp[i]; jb.o[i] = wt[i]; }
  k_pre<<<8899, 256, 0, stream>>>(features, H0, X, Y1, Y2, dst, deg, jb);
  k_offsets<<<(NN+255)/256, 256, 0, stream>>>(deg, row_off, cur, col, total);
  k_fill<<<(NE+255)/256, 256, 0, stream>>>(src, dst, cur, col, NE);

  const int agg_grid  = 3125;
  const int gemm_grid = 512;

  // ---- layer 0 ----
  k_agg<false><<<agg_grid, 256, 0, stream>>>(H0, nullptr, nullptr, nullptr, row_off, deg, col, X);
  k_gemm<4,8,false><<<gemm_grid, 256, 0, stream>>>(X, wt[0], nullptr, nullptr, nullptr, Y1, stats[0]);
  k_gemm<4,8,true ><<<gemm_grid, 256, 0, stream>>>(Y1, wt[1], stats[0], gp[0], bep[0], Y2, stats[1]);
  // ---- layer 1 ----
  k_agg<true ><<<agg_grid, 256, 0, stream>>>(Y2, stats[1], gp[1], bep[1], row_off, deg, col, X);
  k_gemm<4,8,false><<<gemm_grid, 256, 0, stream>>>(X, wt[2], nullptr, nullptr, nullptr, Y1, stats[2]);
  k_gemm<4,8,true ><<<gemm_grid, 256, 0, stream>>>(Y1, wt[3], stats[2], gp[2], bep[2], Y2, stats[3]);
  // ---- layer 2 ----
  k_agg<true ><<<agg_grid, 256, 0, stream>>>(Y2, stats[3], gp[3], bep[3], row_off, deg, col, X);
  k_gemm<4,4,false><<<gemm_grid, 256, 0, stream>>>(X, wt[4], nullptr, nullptr, nullptr, Y1, stats[4]);
  k_gemm<2,4,true ><<<gemm_grid, 256, 0, stream>>>(Y1, wt[5], stats[4], gp[4], bep[4], Y2, stats[5]);
  k_final<<<782, 256, 0, stream>>>(Y2, stats[5], gp[5], bep[5], (float*)d_out);
}